// Round 3
// baseline (540.390 us; speedup 1.0000x reference)
//
#include <hip/hip_runtime.h>
#include <hip/hip_bf16.h>

#define BATCH 1024
#define FDIM  352
#define HDIM  64
#define NT    22          // FDIM / 16

typedef short bf16x8 __attribute__((ext_vector_type(8)));
typedef float f32x4  __attribute__((ext_vector_type(4)));
typedef unsigned short ushort_t;

__device__ __forceinline__ ushort_t f2bf(float x) {
    union { float f; unsigned u; } v; v.f = x;
    unsigned u = v.u;
    unsigned r = u + 0x7FFFu + ((u >> 16) & 1u);   // RNE to bf16
    return (ushort_t)(r >> 16);
}

__device__ __forceinline__ float sigmoidf_(float x) {
    return 1.0f / (1.0f + __expf(-x));
}

// ---------- prep 1: W (x_rep_w) fp32 -> bf16 ----------
__global__ void prep_w(const float* __restrict__ xrepw, ushort_t* __restrict__ wbf) {
    int idx = blockIdx.x * 256 + threadIdx.x;
    if (idx < FDIM * HDIM) wbf[idx] = f2bf(xrepw[idx]);
}

// ---------- prep 2: MT[h][d] = sum_e Qw[e,d]*Kw[e,h]; u0,v0,c ----------
__global__ void prep_m(const float* __restrict__ Qw, const float* __restrict__ Qb,
                       const float* __restrict__ Kw, const float* __restrict__ Kb,
                       float* __restrict__ MT, float* __restrict__ u0,
                       float* __restrict__ v0, float* __restrict__ cS) {
    __shared__ float qs[4096], ks[4096];
    const int t = threadIdx.x, blk = blockIdx.x;
    for (int i = t; i < 4096; i += 256) { qs[i] = Qw[i]; ks[i] = Kw[i]; }
    __syncthreads();
    if (blk < 16) {
        int idx = blk * 256 + t;
        int h = idx >> 6, d = idx & 63;
        float acc = 0.f;
        for (int e = 0; e < 64; ++e) acc = fmaf(qs[e * 64 + d], ks[e * 64 + h], acc);
        MT[h * 64 + d] = acc;
    } else {
        if (t < 64) {
            float a = 0.f;
            for (int e = 0; e < 64; ++e) a = fmaf(qs[e * 64 + t], Kb[e], a);
            u0[t] = a;
        } else if (t < 128) {
            int d = t - 64; float a = 0.f;
            for (int e = 0; e < 64; ++e) a = fmaf(ks[e * 64 + d], Qb[e], a);
            v0[d] = a;
        } else if (t == 128) {
            float a = 0.f;
            for (int e = 0; e < 64; ++e) a = fmaf(Qb[e], Kb[e], a);
            cS[0] = a;
        }
    }
}

// ---------- main fused kernel: one workgroup (4 waves) per batch row ----------
__global__ __launch_bounds__(256, 3) void fused_model(
    const float* __restrict__ X,    const float* __restrict__ Xsp,  const float* __restrict__ Xseq,
    const float* __restrict__ S,    const float* __restrict__ R,
    const float* __restrict__ emb,  const float* __restrict__ xrepw,
    const float* __restrict__ ws1,  const float* __restrict__ bs1,
    const float* __restrict__ wx2,  const float* __restrict__ bx2,
    const float* __restrict__ wsx33,const float* __restrict__ bsx33,
    const float* __restrict__ wr1,  const float* __restrict__ br1,
    const float* __restrict__ wxx2, const float* __restrict__ bxx2,
    const float* __restrict__ wrx33,const float* __restrict__ brx33,
    const float* __restrict__ fc1w, const float* __restrict__ fc1b,
    const float* __restrict__ fc2w, const float* __restrict__ fc2b,
    const float* __restrict__ fc3w, const float* __restrict__ fc3b,
    const ushort_t* __restrict__ wbf, const float* __restrict__ MT,
    const float* __restrict__ u0g,  const float* __restrict__ v0g,
    const float* __restrict__ cS,   float* __restrict__ out)
{
    __shared__ __align__(16) ushort_t plds[FDIM * 64];   // P (=W*Mtilde), bf16, XOR-swizzled cols
    __shared__ float xc[FDIM];
    __shared__ float pu[FDIM], pv[FDIM];
    __shared__ float outa[384];                          // X_attn (352) + sx(16) + rx(16)
    __shared__ float rnorm[HDIM];
    __shared__ float hx[2][HDIM];
    __shared__ float ph[4][HDIM];                        // also aliased as norm partials
    __shared__ float a1[HDIM], a2[HDIM];

    const int b   = blockIdx.x;
    const int t   = threadIdx.x;
    const int l   = t & 63;
    const int wv  = t >> 6;
    const int row = l & 15;
    const int kg  = l >> 4;

    // ---------- Phase A: build Xc, zero outa ----------
    for (int f = t; f < FDIM; f += 256) {
        float v;
        if (f < 64)       v = X[b * 64 + f];
        else if (f < 320) { int i = (f - 64) >> 3, j = (f - 64) & 7; v = Xsp[b * 32 + i] * emb[i * 8 + j]; }
        else              v = Xseq[b * 32 + (f - 320)];
        xc[f] = v;
    }
    for (int f = t; f < 384; f += 256) outa[f] = 0.f;
    __syncthreads();

    // ---------- Phase B: rnorm[d] = 1/||Xrep[:,d]|| (fp32) ----------
    {
        float acc = 0.f;
        for (int f = wv; f < FDIM; f += 4) {
            float v = xc[f] * xrepw[f * 64 + l];
            acc = fmaf(v, v, acc);
        }
        float* pf = &ph[0][0];
        pf[wv * 64 + l] = acc;
        __syncthreads();
        if (t < 64) rnorm[t] = rsqrtf(pf[t] + pf[64 + t] + pf[128 + t] + pf[192 + t]);
        __syncthreads();
    }

    // ---------- Phase C: B-frags of [Mtilde | u~ | v~] (5 n-tiles), bf16, in regs ----------
    bf16x8 bm[5][2];
    {
        float rd[16];
        #pragma unroll
        for (int s = 0; s < 2; ++s)
            #pragma unroll
            for (int j = 0; j < 8; ++j)
                rd[s * 8 + j] = rnorm[s * 32 + kg * 8 + j];
        #pragma unroll
        for (int n = 0; n < 4; ++n) {
            const float rh = rnorm[n * 16 + row] * 0.125f;
            #pragma unroll
            for (int s = 0; s < 2; ++s) {
                const f32x4* mp = (const f32x4*)&MT[(n * 16 + row) * 64 + s * 32 + kg * 8];
                f32x4 m0 = mp[0], m1 = mp[1];
                bf16x8 v;
                #pragma unroll
                for (int j = 0; j < 4; ++j) {
                    v[j]     = (short)f2bf(rd[s * 8 + j]     * m0[j] * rh);
                    v[j + 4] = (short)f2bf(rd[s * 8 + j + 4] * m1[j] * rh);
                }
                bm[n][s] = v;
            }
        }
        #pragma unroll
        for (int s = 0; s < 2; ++s) {
            bf16x8 v = {0, 0, 0, 0, 0, 0, 0, 0};
            if (row < 2) {
                const float* src = (row == 0) ? u0g : v0g;
                const f32x4* up = (const f32x4*)&src[s * 32 + kg * 8];
                f32x4 a0 = up[0], a1v = up[1];
                #pragma unroll
                for (int j = 0; j < 4; ++j) {
                    v[j]     = (short)f2bf(rd[s * 8 + j]     * a0[j]  * 0.125f);
                    v[j + 4] = (short)f2bf(rd[s * 8 + j + 4] * a1v[j] * 0.125f);
                }
            }
            bm[4][s] = v;
        }
    }

    // ---------- Phase G1: P = W @ [Mtilde | u~ | v~]  ->  plds (bf16) + pu/pv (fp32) ----------
    for (int mt = wv; mt < NT; mt += 4) {
        const int f0 = mt * 16;
        const bf16x8 aw0 = *(const bf16x8*)&wbf[(f0 + row) * 64 + kg * 8];
        const bf16x8 aw1 = *(const bf16x8*)&wbf[(f0 + row) * 64 + 32 + kg * 8];
        f32x4 p[5];
        #pragma unroll
        for (int n = 0; n < 5; ++n) {
            f32x4 a = {0.f, 0.f, 0.f, 0.f};
            a = __builtin_amdgcn_mfma_f32_16x16x32_bf16(aw0, bm[n][0], a, 0, 0, 0);
            a = __builtin_amdgcn_mfma_f32_16x16x32_bf16(aw1, bm[n][1], a, 0, 0, 0);
            p[n] = a;
        }
        #pragma unroll
        for (int r = 0; r < 4; ++r) {
            const int f = f0 + kg * 4 + r;
            const int sw = (f & 7) << 3;
            #pragma unroll
            for (int n = 0; n < 4; ++n)
                plds[f * 64 + ((n * 16 + row) ^ sw)] = f2bf(p[n][r]);
            if (row == 0)      pu[f] = p[4][r];
            else if (row == 1) pv[f] = p[4][r];
        }
    }
    __syncthreads();

    // ---------- Phase G2: scores = Xc_f*Xc_g*(P W^T) + Xc_f*Pu_f + Xc_g*Pv_g + c ----------
    //            row-softmax over g, accumulate X_attn[g]
    {
        const float cg = cS[0] * 0.125f;
        for (int mt = wv; mt < NT; mt += 4) {
            const int f0 = mt * 16;
            const int swr = (row & 7) << 3;
            const bf16x8 ap0 = *(const bf16x8*)&plds[(f0 + row) * 64 + ((kg * 8) ^ swr)];
            const bf16x8 ap1 = *(const bf16x8*)&plds[(f0 + row) * 64 + ((32 + kg * 8) ^ swr)];

            f32x4 acc[NT];
            #pragma unroll
            for (int nt = 0; nt < NT; ++nt) {
                const int g = nt * 16 + row;
                bf16x8 b0 = *(const bf16x8*)&wbf[g * 64 + kg * 8];
                bf16x8 b1 = *(const bf16x8*)&wbf[g * 64 + 32 + kg * 8];
                f32x4 a = {0.f, 0.f, 0.f, 0.f};
                a = __builtin_amdgcn_mfma_f32_16x16x32_bf16(ap0, b0, a, 0, 0, 0);
                a = __builtin_amdgcn_mfma_f32_16x16x32_bf16(ap1, b1, a, 0, 0, 0);
                acc[nt] = a;
            }

            float xf[4], uf[4];
            #pragma unroll
            for (int r = 0; r < 4; ++r) {
                const int f = f0 + kg * 4 + r;
                xf[r] = xc[f];
                uf[r] = fmaf(xf[r], pu[f], cg);
            }
            float m[4] = {-1e30f, -1e30f, -1e30f, -1e30f};
            #pragma unroll
            for (int nt = 0; nt < NT; ++nt) {
                const int g = nt * 16 + row;
                const float xg = xc[g];
                const float vg = xg * pv[g];
                #pragma unroll
                for (int r = 0; r < 4; ++r) {
                    float s = fmaf(xf[r] * xg, acc[nt][r], uf[r] + vg);
                    acc[nt][r] = s;
                    m[r] = fmaxf(m[r], s);
                }
            }
            #pragma unroll
            for (int r = 0; r < 4; ++r) {
                #pragma unroll
                for (int off = 1; off < 16; off <<= 1)
                    m[r] = fmaxf(m[r], __shfl_xor(m[r], off, 64));
            }
            float lsum[4] = {0.f, 0.f, 0.f, 0.f};
            #pragma unroll
            for (int nt = 0; nt < NT; ++nt) {
                #pragma unroll
                for (int r = 0; r < 4; ++r) {
                    float p = __expf(acc[nt][r] - m[r]);
                    acc[nt][r] = p;
                    lsum[r] += p;
                }
            }
            #pragma unroll
            for (int r = 0; r < 4; ++r) {
                #pragma unroll
                for (int off = 1; off < 16; off <<= 1)
                    lsum[r] += __shfl_xor(lsum[r], off, 64);
            }
            float coef[4];
            #pragma unroll
            for (int r = 0; r < 4; ++r) coef[r] = xf[r] / lsum[r];
            #pragma unroll
            for (int nt = 0; nt < NT; ++nt) {
                float po = coef[0] * acc[nt][0] + coef[1] * acc[nt][1]
                         + coef[2] * acc[nt][2] + coef[3] * acc[nt][3];
                po += __shfl_xor(po, 16, 64);
                po += __shfl_xor(po, 32, 64);
                if (l < 16) atomicAdd(&outa[nt * 16 + l], po);
            }
        }
    }
    __syncthreads();

    // ---------- Phase H: h_x = sigmoid(Xc @ w2^T + b2), both branches, 4 waves ----------
    {
        const int br = wv >> 1, fh = wv & 1;
        const float* w2 = br ? wxx2 : wx2;
        const int fo = l & 3, hb = l >> 2;
        float acc[4] = {0.f, 0.f, 0.f, 0.f};
        for (int k = 0; k < 44; ++k) {
            const int f = fh * 176 + fo + k * 4;
            const float xv = xc[f];
            #pragma unroll
            for (int c = 0; c < 4; ++c)
                acc[c] = fmaf(xv, w2[(hb + 16 * c) * FDIM + f], acc[c]);
        }
        #pragma unroll
        for (int c = 0; c < 4; ++c) {
            acc[c] += __shfl_xor(acc[c], 1, 64);
            acc[c] += __shfl_xor(acc[c], 2, 64);
        }
        if (fo == 0) {
            #pragma unroll
            for (int c = 0; c < 4; ++c) ph[wv][hb + 16 * c] = acc[c];
        }
    }
    __syncthreads();
    if (t < 128) {
        const int br = t >> 6, h = t & 63;
        const float* b2 = br ? bxx2 : bx2;
        hx[br][h] = sigmoidf_(ph[br * 2][h] + ph[br * 2 + 1][h] + b2[h]);
    }
    __syncthreads();

    // ---------- Phase I: interaction attention (wave0=S, wave1=R) ----------
    if (wv < 2) {
        const float* sv  = wv ? R     : S;
        const float* w1  = wv ? wr1   : ws1;
        const float* b1  = wv ? br1   : bs1;
        const float* w33 = wv ? wrx33 : wsx33;
        const float  b33 = wv ? brx33[0] : bsx33[0];
        const int i = l >> 2, ho = l & 3;
        const float si = sv[b * 16 + i];
        float v = 0.f;
        for (int k = 0; k < 16; ++k) {
            const int h = ho * 16 + k;
            float hs = sigmoidf_(fmaf(si, w1[h], b1[h]));
            v = fmaf(fmaxf(hs + hx[wv][h], 0.f), w33[h], v);
        }
        v += __shfl_xor(v, 1, 64);
        v += __shfl_xor(v, 2, 64);
        const float sc = v + b33;
        float mm = sc;
        #pragma unroll
        for (int off = 4; off < 64; off <<= 1) mm = fmaxf(mm, __shfl_xor(mm, off, 64));
        const float p = __expf(sc - mm);
        float ss = p;
        #pragma unroll
        for (int off = 4; off < 64; off <<= 1) ss += __shfl_xor(ss, off, 64);
        // ss = sum over the 16 distinct p_i (one per 4-lane group) — no replication factor
        if (ho == 0) outa[FDIM + wv * 16 + i] = si * (p / ss);
    }
    __syncthreads();

    // ---------- Phase J: MLP head ----------
    {   // fc1: [64 x 384]
        const int h = t >> 2, jo = t & 3;
        float acc = 0.f;
        for (int j = jo; j < 384; j += 4)
            acc = fmaf(outa[j], fc1w[h * 384 + j], acc);
        acc += __shfl_xor(acc, 1, 64);
        acc += __shfl_xor(acc, 2, 64);
        if (jo == 0) a1[h] = fmaxf(acc + fc1b[h], 0.f);
    }
    __syncthreads();
    {   // fc2: [64 x 64]
        const int h = t >> 2, jo = t & 3;
        float acc = 0.f;
        #pragma unroll
        for (int j = jo; j < 64; j += 4)
            acc = fmaf(a1[j], fc2w[h * 64 + j], acc);
        acc += __shfl_xor(acc, 1, 64);
        acc += __shfl_xor(acc, 2, 64);
        if (jo == 0) a2[h] = fmaxf(acc + fc2b[h], 0.f);
    }
    __syncthreads();
    if (wv == 0) {   // fc3: [1 x 64]
        float v = fc3w[l] * a2[l];
        #pragma unroll
        for (int off = 1; off < 64; off <<= 1) v += __shfl_xor(v, off, 64);
        if (l == 0) out[b] = v + fc3b[0];
    }
}

extern "C" void kernel_launch(void* const* d_in, const int* in_sizes, int n_in,
                              void* d_out, int out_size, void* d_ws, size_t ws_size,
                              hipStream_t stream) {
    const float* X     = (const float*)d_in[0];
    const float* Xsp   = (const float*)d_in[1];
    const float* Xseq  = (const float*)d_in[2];
    const float* S     = (const float*)d_in[3];
    const float* R     = (const float*)d_in[4];
    const float* emb   = (const float*)d_in[5];
    const float* xrepw = (const float*)d_in[6];
    const float* Qw    = (const float*)d_in[7];
    const float* Qb    = (const float*)d_in[8];
    const float* Kw    = (const float*)d_in[9];
    const float* Kb    = (const float*)d_in[10];
    // d_in[11], d_in[12] = Vw, Vb : dead code in reference (attn@V unused)
    const float* ws1   = (const float*)d_in[13];
    const float* bs1   = (const float*)d_in[14];
    const float* wx2   = (const float*)d_in[15];
    const float* bx2   = (const float*)d_in[16];
    const float* wsx33 = (const float*)d_in[17];
    const float* bsx33 = (const float*)d_in[18];
    const float* wr1   = (const float*)d_in[19];
    const float* br1   = (const float*)d_in[20];
    const float* wxx2  = (const float*)d_in[21];
    const float* bxx2  = (const float*)d_in[22];
    const float* wrx33 = (const float*)d_in[23];
    const float* brx33 = (const float*)d_in[24];
    const float* fc1w  = (const float*)d_in[25];
    const float* fc1b  = (const float*)d_in[26];
    const float* fc2w  = (const float*)d_in[27];
    const float* fc2b  = (const float*)d_in[28];
    const float* fc3w  = (const float*)d_in[29];
    const float* fc3b  = (const float*)d_in[30];

    char* ws = (char*)d_ws;
    ushort_t* wbf = (ushort_t*)(ws);            // 352*64*2 = 45056 B
    float*    MTp = (float*)(ws + 45056);       // 64*64*4  = 16384 B
    float*    u0  = (float*)(ws + 61440);       // 256 B
    float*    v0  = (float*)(ws + 61696);       // 256 B
    float*    cS  = (float*)(ws + 61952);       // 4 B

    prep_w<<<(FDIM * HDIM + 255) / 256, 256, 0, stream>>>(xrepw, wbf);
    prep_m<<<17, 256, 0, stream>>>(Qw, Qb, Kw, Kb, MTp, u0, v0, cS);
    fused_model<<<BATCH, 256, 0, stream>>>(
        X, Xsp, Xseq, S, R, emb, xrepw,
        ws1, bs1, wx2, bx2, wsx33, bsx33,
        wr1, br1, wxx2, bxx2, wrx33, brx33,
        fc1w, fc1b, fc2w, fc2b, fc3w, fc3b,
        wbf, MTp, u0, v0, cS, (float*)d_out);
}

// Round 4
// 418.879 us; speedup vs baseline: 1.2901x; 1.2901x over previous
//
#include <hip/hip_runtime.h>
#include <hip/hip_bf16.h>

#define BATCH 1024
#define FDIM  352
#define HDIM  64
#define NT    22          // FDIM / 16

typedef short bf16x8 __attribute__((ext_vector_type(8)));
typedef float f32x4  __attribute__((ext_vector_type(4)));
typedef unsigned short ushort_t;

__device__ __forceinline__ ushort_t f2bf(float x) {
    union { float f; unsigned u; } v; v.f = x;
    unsigned u = v.u;
    unsigned r = u + 0x7FFFu + ((u >> 16) & 1u);   // RNE to bf16
    return (ushort_t)(r >> 16);
}

__device__ __forceinline__ float sigmoidf_(float x) {
    return 1.0f / (1.0f + __expf(-x));
}

// ---------- prep 1: W (x_rep_w) fp32 -> bf16 ----------
__global__ void prep_w(const float* __restrict__ xrepw, ushort_t* __restrict__ wbf) {
    int idx = blockIdx.x * 256 + threadIdx.x;
    if (idx < FDIM * HDIM) wbf[idx] = f2bf(xrepw[idx]);
}

// ---------- prep 2: MT[h][d] = sum_e Qw[e,d]*Kw[e,h]; u0,v0,c ----------
__global__ void prep_m(const float* __restrict__ Qw, const float* __restrict__ Qb,
                       const float* __restrict__ Kw, const float* __restrict__ Kb,
                       float* __restrict__ MT, float* __restrict__ u0,
                       float* __restrict__ v0, float* __restrict__ cS) {
    __shared__ float qs[4096], ks[4096];
    const int t = threadIdx.x, blk = blockIdx.x;
    for (int i = t; i < 4096; i += 256) { qs[i] = Qw[i]; ks[i] = Kw[i]; }
    __syncthreads();
    if (blk < 16) {
        int idx = blk * 256 + t;
        int h = idx >> 6, d = idx & 63;
        float acc = 0.f;
        for (int e = 0; e < 64; ++e) acc = fmaf(qs[e * 64 + d], ks[e * 64 + h], acc);
        MT[h * 64 + d] = acc;
    } else {
        if (t < 64) {
            float a = 0.f;
            for (int e = 0; e < 64; ++e) a = fmaf(qs[e * 64 + t], Kb[e], a);
            u0[t] = a;
        } else if (t < 128) {
            int d = t - 64; float a = 0.f;
            for (int e = 0; e < 64; ++e) a = fmaf(ks[e * 64 + d], Qb[e], a);
            v0[d] = a;
        } else if (t == 128) {
            float a = 0.f;
            for (int e = 0; e < 64; ++e) a = fmaf(Qb[e], Kb[e], a);
            cS[0] = a;
        }
    }
}

// ---------- main fused kernel: one workgroup (4 waves) per batch row ----------
__global__ __launch_bounds__(256, 3) void fused_model(
    const float* __restrict__ X,    const float* __restrict__ Xsp,  const float* __restrict__ Xseq,
    const float* __restrict__ S,    const float* __restrict__ R,
    const float* __restrict__ emb,  const float* __restrict__ xrepw,
    const float* __restrict__ ws1,  const float* __restrict__ bs1,
    const float* __restrict__ wx2,  const float* __restrict__ bx2,
    const float* __restrict__ wsx33,const float* __restrict__ bsx33,
    const float* __restrict__ wr1,  const float* __restrict__ br1,
    const float* __restrict__ wxx2, const float* __restrict__ bxx2,
    const float* __restrict__ wrx33,const float* __restrict__ brx33,
    const float* __restrict__ fc1w, const float* __restrict__ fc1b,
    const float* __restrict__ fc2w, const float* __restrict__ fc2b,
    const float* __restrict__ fc3w, const float* __restrict__ fc3b,
    const ushort_t* __restrict__ wbf, const float* __restrict__ MT,
    const float* __restrict__ u0g,  const float* __restrict__ v0g,
    const float* __restrict__ cS,   float* __restrict__ out)
{
    __shared__ __align__(16) ushort_t plds[FDIM * 64];   // P (=W*Mtilde), bf16, XOR-swizzled cols
    __shared__ float xc[FDIM];
    __shared__ float pu[FDIM], pv[FDIM];
    __shared__ float outa[384];                          // X_attn (352) + sx(16) + rx(16)
    __shared__ float rnorm[HDIM];
    __shared__ float hx[2][HDIM];
    __shared__ float ph[4][HDIM];                        // also aliased as norm partials
    __shared__ float a1[HDIM], a2[HDIM];

    const int b   = blockIdx.x;
    const int t   = threadIdx.x;
    const int l   = t & 63;
    const int wv  = t >> 6;
    const int row = l & 15;
    const int kg  = l >> 4;

    // ---------- Phase A: build Xc, zero outa ----------
    for (int f = t; f < FDIM; f += 256) {
        float v;
        if (f < 64)       v = X[b * 64 + f];
        else if (f < 320) { int i = (f - 64) >> 3, j = (f - 64) & 7; v = Xsp[b * 32 + i] * emb[i * 8 + j]; }
        else              v = Xseq[b * 32 + (f - 320)];
        xc[f] = v;
    }
    for (int f = t; f < 384; f += 256) outa[f] = 0.f;
    __syncthreads();

    // ---------- Phase B: rnorm[d] = 1/||Xrep[:,d]|| (fp32) ----------
    {
        float acc = 0.f;
        for (int f = wv; f < FDIM; f += 4) {
            float v = xc[f] * xrepw[f * 64 + l];
            acc = fmaf(v, v, acc);
        }
        float* pf = &ph[0][0];
        pf[wv * 64 + l] = acc;
        __syncthreads();
        if (t < 64) rnorm[t] = rsqrtf(pf[t] + pf[64 + t] + pf[128 + t] + pf[192 + t]);
        __syncthreads();
    }

    // ---------- Phase C: B-frags of [Mtilde | u~ | v~] (5 n-tiles), bf16, in regs ----------
    bf16x8 bm[5][2];
    {
        float rd[16];
        #pragma unroll
        for (int s = 0; s < 2; ++s)
            #pragma unroll
            for (int j = 0; j < 8; ++j)
                rd[s * 8 + j] = rnorm[s * 32 + kg * 8 + j];
        #pragma unroll
        for (int n = 0; n < 4; ++n) {
            const float rh = rnorm[n * 16 + row] * 0.125f;
            #pragma unroll
            for (int s = 0; s < 2; ++s) {
                const f32x4* mp = (const f32x4*)&MT[(n * 16 + row) * 64 + s * 32 + kg * 8];
                f32x4 m0 = mp[0], m1 = mp[1];
                bf16x8 v;
                #pragma unroll
                for (int j = 0; j < 4; ++j) {
                    v[j]     = (short)f2bf(rd[s * 8 + j]     * m0[j] * rh);
                    v[j + 4] = (short)f2bf(rd[s * 8 + j + 4] * m1[j] * rh);
                }
                bm[n][s] = v;
            }
        }
        #pragma unroll
        for (int s = 0; s < 2; ++s) {
            bf16x8 v = {0, 0, 0, 0, 0, 0, 0, 0};
            if (row < 2) {
                const float* src = (row == 0) ? u0g : v0g;
                const f32x4* up = (const f32x4*)&src[s * 32 + kg * 8];
                f32x4 a0 = up[0], a1v = up[1];
                #pragma unroll
                for (int j = 0; j < 4; ++j) {
                    v[j]     = (short)f2bf(rd[s * 8 + j]     * a0[j]  * 0.125f);
                    v[j + 4] = (short)f2bf(rd[s * 8 + j + 4] * a1v[j] * 0.125f);
                }
            }
            bm[4][s] = v;
        }
    }

    // ---------- Phase G1: P = W @ [Mtilde | u~ | v~]  ->  plds (bf16) + pu/pv (fp32) ----------
    // Compile-time trip count (6 unrolled copies, wave-uniform guard) so all arrays
    // stay in registers — round-3's runtime-trip loop spilled acc to scratch (216 MB writes).
    #pragma unroll
    for (int imt = 0; imt < 6; ++imt) {
        const int mt = wv + imt * 4;
        if (mt < NT) {
            const int f0 = mt * 16;
            const bf16x8 aw0 = *(const bf16x8*)&wbf[(f0 + row) * 64 + kg * 8];
            const bf16x8 aw1 = *(const bf16x8*)&wbf[(f0 + row) * 64 + 32 + kg * 8];
            f32x4 p[5];
            #pragma unroll
            for (int n = 0; n < 5; ++n) {
                f32x4 a = {0.f, 0.f, 0.f, 0.f};
                a = __builtin_amdgcn_mfma_f32_16x16x32_bf16(aw0, bm[n][0], a, 0, 0, 0);
                a = __builtin_amdgcn_mfma_f32_16x16x32_bf16(aw1, bm[n][1], a, 0, 0, 0);
                p[n] = a;
            }
            #pragma unroll
            for (int r = 0; r < 4; ++r) {
                const int f = f0 + kg * 4 + r;
                const int sw = (f & 7) << 3;
                #pragma unroll
                for (int n = 0; n < 4; ++n)
                    plds[f * 64 + ((n * 16 + row) ^ sw)] = f2bf(p[n][r]);
                if (row == 0)      pu[f] = p[4][r];
                else if (row == 1) pv[f] = p[4][r];
            }
        }
    }
    __syncthreads();

    // ---------- Phase G2: scores = Xc_f*Xc_g*(P W^T) + Xc_f*Pu_f + Xc_g*Pv_g + c ----------
    //            row-softmax over g (no max pass: |s| = O(1), exp cannot overflow),
    //            accumulate X_attn[g]
    {
        const float cg = cS[0] * 0.125f;
        #pragma unroll
        for (int imt = 0; imt < 6; ++imt) {
            const int mt = wv + imt * 4;
            if (mt < NT) {
                const int f0 = mt * 16;
                const int swr = (row & 7) << 3;
                const bf16x8 ap0 = *(const bf16x8*)&plds[(f0 + row) * 64 + ((kg * 8) ^ swr)];
                const bf16x8 ap1 = *(const bf16x8*)&plds[(f0 + row) * 64 + ((32 + kg * 8) ^ swr)];

                f32x4 acc[NT];
                #pragma unroll
                for (int nt = 0; nt < NT; ++nt) {
                    const int g = nt * 16 + row;
                    bf16x8 b0 = *(const bf16x8*)&wbf[g * 64 + kg * 8];
                    bf16x8 b1 = *(const bf16x8*)&wbf[g * 64 + 32 + kg * 8];
                    f32x4 a = {0.f, 0.f, 0.f, 0.f};
                    a = __builtin_amdgcn_mfma_f32_16x16x32_bf16(ap0, b0, a, 0, 0, 0);
                    a = __builtin_amdgcn_mfma_f32_16x16x32_bf16(ap1, b1, a, 0, 0, 0);
                    acc[nt] = a;
                }

                float xf[4], uf[4];
                #pragma unroll
                for (int r = 0; r < 4; ++r) {
                    const int f = f0 + kg * 4 + r;
                    xf[r] = xc[f];
                    uf[r] = fmaf(xf[r], pu[f], cg);
                }
                float lsum[4] = {0.f, 0.f, 0.f, 0.f};
                #pragma unroll
                for (int nt = 0; nt < NT; ++nt) {
                    const int g = nt * 16 + row;
                    const float xg = xc[g];
                    const float vg = xg * pv[g];
                    #pragma unroll
                    for (int r = 0; r < 4; ++r) {
                        float s = fmaf(xf[r] * xg, acc[nt][r], uf[r] + vg);
                        float p = __expf(s);
                        acc[nt][r] = p;
                        lsum[r] += p;
                    }
                }
                #pragma unroll
                for (int r = 0; r < 4; ++r) {
                    #pragma unroll
                    for (int off = 1; off < 16; off <<= 1)
                        lsum[r] += __shfl_xor(lsum[r], off, 64);
                }
                float coef[4];
                #pragma unroll
                for (int r = 0; r < 4; ++r) coef[r] = xf[r] / lsum[r];
                #pragma unroll
                for (int nt = 0; nt < NT; ++nt) {
                    float po = coef[0] * acc[nt][0] + coef[1] * acc[nt][1]
                             + coef[2] * acc[nt][2] + coef[3] * acc[nt][3];
                    po += __shfl_xor(po, 16, 64);
                    po += __shfl_xor(po, 32, 64);
                    if (l < 16) atomicAdd(&outa[nt * 16 + l], po);
                }
            }
        }
    }
    __syncthreads();

    // ---------- Phase H: h_x = sigmoid(Xc @ w2^T + b2), both branches, 4 waves ----------
    {
        const int br = wv >> 1, fh = wv & 1;
        const float* w2 = br ? wxx2 : wx2;
        const int fo = l & 3, hb = l >> 2;
        float acc[4] = {0.f, 0.f, 0.f, 0.f};
        for (int k = 0; k < 44; ++k) {
            const int f = fh * 176 + fo + k * 4;
            const float xv = xc[f];
            #pragma unroll
            for (int c = 0; c < 4; ++c)
                acc[c] = fmaf(xv, w2[(hb + 16 * c) * FDIM + f], acc[c]);
        }
        #pragma unroll
        for (int c = 0; c < 4; ++c) {
            acc[c] += __shfl_xor(acc[c], 1, 64);
            acc[c] += __shfl_xor(acc[c], 2, 64);
        }
        if (fo == 0) {
            #pragma unroll
            for (int c = 0; c < 4; ++c) ph[wv][hb + 16 * c] = acc[c];
        }
    }
    __syncthreads();
    if (t < 128) {
        const int br = t >> 6, h = t & 63;
        const float* b2 = br ? bxx2 : bx2;
        hx[br][h] = sigmoidf_(ph[br * 2][h] + ph[br * 2 + 1][h] + b2[h]);
    }
    __syncthreads();

    // ---------- Phase I: interaction attention (wave0=S, wave1=R) ----------
    if (wv < 2) {
        const float* sv  = wv ? R     : S;
        const float* w1  = wv ? wr1   : ws1;
        const float* b1  = wv ? br1   : bs1;
        const float* w33 = wv ? wrx33 : wsx33;
        const float  b33 = wv ? brx33[0] : bsx33[0];
        const int i = l >> 2, ho = l & 3;
        const float si = sv[b * 16 + i];
        float v = 0.f;
        for (int k = 0; k < 16; ++k) {
            const int h = ho * 16 + k;
            float hs = sigmoidf_(fmaf(si, w1[h], b1[h]));
            v = fmaf(fmaxf(hs + hx[wv][h], 0.f), w33[h], v);
        }
        v += __shfl_xor(v, 1, 64);
        v += __shfl_xor(v, 2, 64);
        const float sc = v + b33;
        float mm = sc;
        #pragma unroll
        for (int off = 4; off < 64; off <<= 1) mm = fmaxf(mm, __shfl_xor(mm, off, 64));
        const float p = __expf(sc - mm);
        float ss = p;
        #pragma unroll
        for (int off = 4; off < 64; off <<= 1) ss += __shfl_xor(ss, off, 64);
        // ss = sum over the 16 distinct p_i (one per 4-lane group) — no replication factor
        if (ho == 0) outa[FDIM + wv * 16 + i] = si * (p / ss);
    }
    __syncthreads();

    // ---------- Phase J: MLP head ----------
    {   // fc1: [64 x 384]
        const int h = t >> 2, jo = t & 3;
        float acc = 0.f;
        for (int j = jo; j < 384; j += 4)
            acc = fmaf(outa[j], fc1w[h * 384 + j], acc);
        acc += __shfl_xor(acc, 1, 64);
        acc += __shfl_xor(acc, 2, 64);
        if (jo == 0) a1[h] = fmaxf(acc + fc1b[h], 0.f);
    }
    __syncthreads();
    {   // fc2: [64 x 64]
        const int h = t >> 2, jo = t & 3;
        float acc = 0.f;
        #pragma unroll
        for (int j = jo; j < 64; j += 4)
            acc = fmaf(a1[j], fc2w[h * 64 + j], acc);
        acc += __shfl_xor(acc, 1, 64);
        acc += __shfl_xor(acc, 2, 64);
        if (jo == 0) a2[h] = fmaxf(acc + fc2b[h], 0.f);
    }
    __syncthreads();
    if (wv == 0) {   // fc3: [1 x 64]
        float v = fc3w[l] * a2[l];
        #pragma unroll
        for (int off = 1; off < 64; off <<= 1) v += __shfl_xor(v, off, 64);
        if (l == 0) out[b] = v + fc3b[0];
    }
}

extern "C" void kernel_launch(void* const* d_in, const int* in_sizes, int n_in,
                              void* d_out, int out_size, void* d_ws, size_t ws_size,
                              hipStream_t stream) {
    const float* X     = (const float*)d_in[0];
    const float* Xsp   = (const float*)d_in[1];
    const float* Xseq  = (const float*)d_in[2];
    const float* S     = (const float*)d_in[3];
    const float* R     = (const float*)d_in[4];
    const float* emb   = (const float*)d_in[5];
    const float* xrepw = (const float*)d_in[6];
    const float* Qw    = (const float*)d_in[7];
    const float* Qb    = (const float*)d_in[8];
    const float* Kw    = (const float*)d_in[9];
    const float* Kb    = (const float*)d_in[10];
    // d_in[11], d_in[12] = Vw, Vb : dead code in reference (attn@V unused)
    const float* ws1   = (const float*)d_in[13];
    const float* bs1   = (const float*)d_in[14];
    const float* wx2   = (const float*)d_in[15];
    const float* bx2   = (const float*)d_in[16];
    const float* wsx33 = (const float*)d_in[17];
    const float* bsx33 = (const float*)d_in[18];
    const float* wr1   = (const float*)d_in[19];
    const float* br1   = (const float*)d_in[20];
    const float* wxx2  = (const float*)d_in[21];
    const float* bxx2  = (const float*)d_in[22];
    const float* wrx33 = (const float*)d_in[23];
    const float* brx33 = (const float*)d_in[24];
    const float* fc1w  = (const float*)d_in[25];
    const float* fc1b  = (const float*)d_in[26];
    const float* fc2w  = (const float*)d_in[27];
    const float* fc2b  = (const float*)d_in[28];
    const float* fc3w  = (const float*)d_in[29];
    const float* fc3b  = (const float*)d_in[30];

    char* ws = (char*)d_ws;
    ushort_t* wbf = (ushort_t*)(ws);            // 352*64*2 = 45056 B
    float*    MTp = (float*)(ws + 45056);       // 64*64*4  = 16384 B
    float*    u0  = (float*)(ws + 61440);       // 256 B
    float*    v0  = (float*)(ws + 61696);       // 256 B
    float*    cS  = (float*)(ws + 61952);       // 4 B

    prep_w<<<(FDIM * HDIM + 255) / 256, 256, 0, stream>>>(xrepw, wbf);
    prep_m<<<17, 256, 0, stream>>>(Qw, Qb, Kw, Kb, MTp, u0, v0, cS);
    fused_model<<<BATCH, 256, 0, stream>>>(
        X, Xsp, Xseq, S, R, emb, xrepw,
        ws1, bs1, wx2, bx2, wsx33, bsx33,
        wr1, br1, wxx2, bxx2, wrx33, brx33,
        fc1w, fc1b, fc2w, fc2b, fc3w, fc3b,
        wbf, MTp, u0, v0, cS, (float*)d_out);
}

// Round 6
// 362.170 us; speedup vs baseline: 1.4921x; 1.1566x over previous
//
#include <hip/hip_runtime.h>
#include <hip/hip_bf16.h>

#define BATCH 1024
#define FDIM  352
#define FPAD  384
#define HDIM  64
#define NT    22          // real n-tiles (g < 352)

typedef short bf16x8 __attribute__((ext_vector_type(8)));
typedef float f32x4  __attribute__((ext_vector_type(4)));
typedef unsigned short ushort_t;

__device__ __forceinline__ ushort_t f2bf(float x) {
    union { float f; unsigned u; } v; v.f = x;
    unsigned u = v.u;
    unsigned r = u + 0x7FFFu + ((u >> 16) & 1u);   // RNE to bf16
    return (ushort_t)(r >> 16);
}

__device__ __forceinline__ float sigmoidf_(float x) {
    return 1.0f / (1.0f + __expf(-x));
}

// ---------- prep 1: W (x_rep_w) fp32 -> bf16, padded to 384 rows (zero tail) ----------
__global__ void prep_w(const float* __restrict__ xrepw, ushort_t* __restrict__ wbf) {
    int idx = blockIdx.x * 256 + threadIdx.x;
    if (idx < FPAD * HDIM) {
        int f = idx >> 6;
        wbf[idx] = (f < FDIM) ? f2bf(xrepw[idx]) : (ushort_t)0;
    }
}

// ---------- prep 2: MT[h][d] = sum_e Qw[e,d]*Kw[e,h]; u0,v0,c ----------
__global__ void prep_m(const float* __restrict__ Qw, const float* __restrict__ Qb,
                       const float* __restrict__ Kw, const float* __restrict__ Kb,
                       float* __restrict__ MT, float* __restrict__ u0,
                       float* __restrict__ v0, float* __restrict__ cS) {
    __shared__ float qs[4096], ks[4096];
    const int t = threadIdx.x, blk = blockIdx.x;
    for (int i = t; i < 4096; i += 256) { qs[i] = Qw[i]; ks[i] = Kw[i]; }
    __syncthreads();
    if (blk < 16) {
        int idx = blk * 256 + t;
        int h = idx >> 6, d = idx & 63;
        float acc = 0.f;
        for (int e = 0; e < 64; ++e) acc = fmaf(qs[e * 64 + d], ks[e * 64 + h], acc);
        MT[h * 64 + d] = acc;
    } else {
        if (t < 64) {
            float a = 0.f;
            for (int e = 0; e < 64; ++e) a = fmaf(qs[e * 64 + t], Kb[e], a);
            u0[t] = a;
        } else if (t < 128) {
            int d = t - 64; float a = 0.f;
            for (int e = 0; e < 64; ++e) a = fmaf(ks[e * 64 + d], Qb[e], a);
            v0[d] = a;
        } else if (t == 128) {
            float a = 0.f;
            for (int e = 0; e < 64; ++e) a = fmaf(Qb[e], Kb[e], a);
            cS[0] = a;
        }
    }
}

// ---------- main fused kernel: one workgroup (4 waves) per batch row ----------
// NOTE: no runtime conditionals in G1/G2 tile loops — wave-dependent guards around
// the acc-defining region demote acc[22]/p[5] to scratch (rounds 3-4: 84 VGPR +
// 128-790 MB scratch traffic). Padded tiles (mt=22,23) run on zero data instead.
__global__ __launch_bounds__(256, 2) void fused_model(
    const float* __restrict__ X,    const float* __restrict__ Xsp,  const float* __restrict__ Xseq,
    const float* __restrict__ S,    const float* __restrict__ R,
    const float* __restrict__ emb,  const float* __restrict__ xrepw,
    const float* __restrict__ ws1,  const float* __restrict__ bs1,
    const float* __restrict__ wx2,  const float* __restrict__ bx2,
    const float* __restrict__ wsx33,const float* __restrict__ bsx33,
    const float* __restrict__ wr1,  const float* __restrict__ br1,
    const float* __restrict__ wxx2, const float* __restrict__ bxx2,
    const float* __restrict__ wrx33,const float* __restrict__ brx33,
    const float* __restrict__ fc1w, const float* __restrict__ fc1b,
    const float* __restrict__ fc2w, const float* __restrict__ fc2b,
    const float* __restrict__ fc3w, const float* __restrict__ fc3b,
    const ushort_t* __restrict__ wbf, const float* __restrict__ MT,
    const float* __restrict__ u0g,  const float* __restrict__ v0g,
    const float* __restrict__ cS,   float* __restrict__ out)
{
    __shared__ __align__(16) ushort_t plds[FPAD * 64];   // P (=W*Mtilde), bf16, XOR-swizzled cols
    __shared__ float xc[FPAD];                           // zero tail 352..383
    __shared__ float pu[FPAD], pv[FPAD];
    __shared__ float outa[384];                          // X_attn (352) + sx(16) + rx(16)
    __shared__ float rnorm[HDIM];
    __shared__ float hx[2][HDIM];
    __shared__ float ph[4][HDIM];                        // also aliased as norm partials
    __shared__ float a1[HDIM], a2[HDIM];

    const int b   = blockIdx.x;
    const int t   = threadIdx.x;
    const int l   = t & 63;
    const int wv  = t >> 6;
    const int row = l & 15;
    const int kg  = l >> 4;

    // ---------- Phase A: build Xc (zero-padded), zero outa ----------
    for (int f = t; f < FPAD; f += 256) {
        float v;
        if (f < 64)       v = X[b * 64 + f];
        else if (f < 320) { int i = (f - 64) >> 3, j = (f - 64) & 7; v = Xsp[b * 32 + i] * emb[i * 8 + j]; }
        else if (f < 352) v = Xseq[b * 32 + (f - 320)];
        else              v = 0.f;
        xc[f] = v;
    }
    for (int f = t; f < 384; f += 256) outa[f] = 0.f;
    __syncthreads();

    // ---------- Phase B: rnorm[d] = 1/||Xrep[:,d]|| (fp32) ----------
    {
        float acc = 0.f;
        for (int f = wv; f < FDIM; f += 4) {
            float v = xc[f] * xrepw[f * 64 + l];
            acc = fmaf(v, v, acc);
        }
        float* pf = &ph[0][0];
        pf[wv * 64 + l] = acc;
        __syncthreads();
        if (t < 64) rnorm[t] = rsqrtf(pf[t] + pf[64 + t] + pf[128 + t] + pf[192 + t]);
        __syncthreads();
    }

    // ---------- Phase C: B-frags of [Mtilde | u~ | v~] (5 n-tiles), bf16, in regs ----------
    bf16x8 bm[5][2];
    {
        float rd[16];
        #pragma unroll
        for (int s = 0; s < 2; ++s)
            #pragma unroll
            for (int j = 0; j < 8; ++j)
                rd[s * 8 + j] = rnorm[s * 32 + kg * 8 + j];
        #pragma unroll
        for (int n = 0; n < 4; ++n) {
            const float rh = rnorm[n * 16 + row] * 0.125f;
            #pragma unroll
            for (int s = 0; s < 2; ++s) {
                const f32x4* mp = (const f32x4*)&MT[(n * 16 + row) * 64 + s * 32 + kg * 8];
                f32x4 m0 = mp[0], m1 = mp[1];
                bf16x8 v;
                #pragma unroll
                for (int j = 0; j < 4; ++j) {
                    v[j]     = (short)f2bf(rd[s * 8 + j]     * m0[j] * rh);
                    v[j + 4] = (short)f2bf(rd[s * 8 + j + 4] * m1[j] * rh);
                }
                bm[n][s] = v;
            }
        }
        #pragma unroll
        for (int s = 0; s < 2; ++s) {
            bf16x8 v = {0, 0, 0, 0, 0, 0, 0, 0};
            if (row < 2) {
                const float* src = (row == 0) ? u0g : v0g;
                const f32x4* up = (const f32x4*)&src[s * 32 + kg * 8];
                f32x4 a0 = up[0], a1v = up[1];
                #pragma unroll
                for (int j = 0; j < 4; ++j) {
                    v[j]     = (short)f2bf(rd[s * 8 + j]     * a0[j]  * 0.125f);
                    v[j + 4] = (short)f2bf(rd[s * 8 + j + 4] * a1v[j] * 0.125f);
                }
            }
            bm[4][s] = v;
        }
    }

    // ---------- Phase G1: P = W @ [Mtilde | u~ | v~]  ->  plds (bf16) + pu/pv (fp32) ----------
    // 24 m-tiles, unconditional (tiles 22,23 operate on zero wbf rows -> write zeros)
    #pragma unroll
    for (int imt = 0; imt < 6; ++imt) {
        const int mt = wv + imt * 4;
        const int f0 = mt * 16;
        const bf16x8 aw0 = *(const bf16x8*)&wbf[(f0 + row) * 64 + kg * 8];
        const bf16x8 aw1 = *(const bf16x8*)&wbf[(f0 + row) * 64 + 32 + kg * 8];
        f32x4 p[5];
        #pragma unroll
        for (int n = 0; n < 5; ++n) {
            f32x4 a = {0.f, 0.f, 0.f, 0.f};
            a = __builtin_amdgcn_mfma_f32_16x16x32_bf16(aw0, bm[n][0], a, 0, 0, 0);
            a = __builtin_amdgcn_mfma_f32_16x16x32_bf16(aw1, bm[n][1], a, 0, 0, 0);
            p[n] = a;
        }
        #pragma unroll
        for (int r = 0; r < 4; ++r) {
            const int f = f0 + kg * 4 + r;
            const int sw = (f & 7) << 3;
            #pragma unroll
            for (int n = 0; n < 4; ++n)
                plds[f * 64 + ((n * 16 + row) ^ sw)] = f2bf(p[n][r]);
            if (row == 0)      pu[f] = p[4][r];
            else if (row == 1) pv[f] = p[4][r];
        }
    }
    __syncthreads();

    // ---------- Phase G2: scores = Xc_f*Xc_g*(P W^T) + Xc_f*Pu_f + Xc_g*Pv_g + c ----------
    //            row-softmax over g (no max pass: |s| = O(1)), accumulate X_attn[g].
    //            Padded rows f>=352: xc=0 -> coef=0 -> atomicAdd contributes exactly 0.
    {
        const float cg = cS[0] * 0.125f;
        #pragma unroll
        for (int imt = 0; imt < 6; ++imt) {
            const int mt = wv + imt * 4;
            const int f0 = mt * 16;
            const int swr = (row & 7) << 3;
            const bf16x8 ap0 = *(const bf16x8*)&plds[(f0 + row) * 64 + ((kg * 8) ^ swr)];
            const bf16x8 ap1 = *(const bf16x8*)&plds[(f0 + row) * 64 + ((32 + kg * 8) ^ swr)];

            f32x4 acc[NT];
            #pragma unroll
            for (int nt = 0; nt < NT; ++nt) {
                const int g = nt * 16 + row;
                bf16x8 b0 = *(const bf16x8*)&wbf[g * 64 + kg * 8];
                bf16x8 b1 = *(const bf16x8*)&wbf[g * 64 + 32 + kg * 8];
                f32x4 a = {0.f, 0.f, 0.f, 0.f};
                a = __builtin_amdgcn_mfma_f32_16x16x32_bf16(ap0, b0, a, 0, 0, 0);
                a = __builtin_amdgcn_mfma_f32_16x16x32_bf16(ap1, b1, a, 0, 0, 0);
                acc[nt] = a;
            }

            float xf[4], uf[4];
            #pragma unroll
            for (int r = 0; r < 4; ++r) {
                const int f = f0 + kg * 4 + r;
                xf[r] = xc[f];
                uf[r] = fmaf(xf[r], pu[f], cg);
            }
            float lsum[4] = {0.f, 0.f, 0.f, 0.f};
            #pragma unroll
            for (int nt = 0; nt < NT; ++nt) {
                const int g = nt * 16 + row;
                const float xg = xc[g];
                const float vg = xg * pv[g];
                #pragma unroll
                for (int r = 0; r < 4; ++r) {
                    float s = fmaf(xf[r] * xg, acc[nt][r], uf[r] + vg);
                    float p = __expf(s);
                    acc[nt][r] = p;
                    lsum[r] += p;
                }
            }
            #pragma unroll
            for (int r = 0; r < 4; ++r) {
                #pragma unroll
                for (int off = 1; off < 16; off <<= 1)
                    lsum[r] += __shfl_xor(lsum[r], off, 64);
            }
            float coef[4];
            #pragma unroll
            for (int r = 0; r < 4; ++r) coef[r] = xf[r] / lsum[r];
            #pragma unroll
            for (int nt = 0; nt < NT; ++nt) {
                float po = coef[0] * acc[nt][0] + coef[1] * acc[nt][1]
                         + coef[2] * acc[nt][2] + coef[3] * acc[nt][3];
                po += __shfl_xor(po, 16, 64);
                po += __shfl_xor(po, 32, 64);
                if (l < 16) atomicAdd(&outa[nt * 16 + l], po);
            }
        }
    }
    __syncthreads();

    // ---------- Phase H: h_x = sigmoid(Xc @ w2^T + b2), both branches, 4 waves ----------
    {
        const int br = wv >> 1, fh = wv & 1;
        const float* w2 = br ? wxx2 : wx2;
        const int fo = l & 3, hb = l >> 2;
        float acc[4] = {0.f, 0.f, 0.f, 0.f};
        for (int k = 0; k < 44; ++k) {
            const int f = fh * 176 + fo + k * 4;
            const float xv = xc[f];
            #pragma unroll
            for (int c = 0; c < 4; ++c)
                acc[c] = fmaf(xv, w2[(hb + 16 * c) * FDIM + f], acc[c]);
        }
        #pragma unroll
        for (int c = 0; c < 4; ++c) {
            acc[c] += __shfl_xor(acc[c], 1, 64);
            acc[c] += __shfl_xor(acc[c], 2, 64);
        }
        if (fo == 0) {
            #pragma unroll
            for (int c = 0; c < 4; ++c) ph[wv][hb + 16 * c] = acc[c];
        }
    }
    __syncthreads();
    if (t < 128) {
        const int br = t >> 6, h = t & 63;
        const float* b2 = br ? bxx2 : bx2;
        hx[br][h] = sigmoidf_(ph[br * 2][h] + ph[br * 2 + 1][h] + b2[h]);
    }
    __syncthreads();

    // ---------- Phase I: interaction attention (wave0=S, wave1=R) ----------
    if (wv < 2) {
        const float* sv  = wv ? R     : S;
        const float* w1  = wv ? wr1   : ws1;
        const float* b1  = wv ? br1   : bs1;
        const float* w33 = wv ? wrx33 : wsx33;
        const float  b33 = wv ? brx33[0] : bsx33[0];
        const int i = l >> 2, ho = l & 3;
        const float si = sv[b * 16 + i];
        float v = 0.f;
        for (int k = 0; k < 16; ++k) {
            const int h = ho * 16 + k;
            float hs = sigmoidf_(fmaf(si, w1[h], b1[h]));
            v = fmaf(fmaxf(hs + hx[wv][h], 0.f), w33[h], v);
        }
        v += __shfl_xor(v, 1, 64);
        v += __shfl_xor(v, 2, 64);
        const float sc = v + b33;
        float mm = sc;
        #pragma unroll
        for (int off = 4; off < 64; off <<= 1) mm = fmaxf(mm, __shfl_xor(mm, off, 64));
        const float p = __expf(sc - mm);
        float ss = p;
        #pragma unroll
        for (int off = 4; off < 64; off <<= 1) ss += __shfl_xor(ss, off, 64);
        if (ho == 0) outa[FDIM + wv * 16 + i] = si * (p / ss);
    }
    __syncthreads();

    // ---------- Phase J: MLP head ----------
    {   // fc1: [64 x 384]
        const int h = t >> 2, jo = t & 3;
        float acc = 0.f;
        for (int j = jo; j < 384; j += 4)
            acc = fmaf(outa[j], fc1w[h * 384 + j], acc);
        acc += __shfl_xor(acc, 1, 64);
        acc += __shfl_xor(acc, 2, 64);
        if (jo == 0) a1[h] = fmaxf(acc + fc1b[h], 0.f);
    }
    __syncthreads();
    {   // fc2: [64 x 64]
        const int h = t >> 2, jo = t & 3;
        float acc = 0.f;
        #pragma unroll
        for (int j = jo; j < 64; j += 4)
            acc = fmaf(a1[j], fc2w[h * 64 + j], acc);
        acc += __shfl_xor(acc, 1, 64);
        acc += __shfl_xor(acc, 2, 64);
        if (jo == 0) a2[h] = fmaxf(acc + fc2b[h], 0.f);
    }
    __syncthreads();
    if (wv == 0) {   // fc3: [1 x 64]
        float v = fc3w[l] * a2[l];
        #pragma unroll
        for (int off = 1; off < 64; off <<= 1) v += __shfl_xor(v, off, 64);
        if (l == 0) out[b] = v + fc3b[0];
    }
}

extern "C" void kernel_launch(void* const* d_in, const int* in_sizes, int n_in,
                              void* d_out, int out_size, void* d_ws, size_t ws_size,
                              hipStream_t stream) {
    const float* X     = (const float*)d_in[0];
    const float* Xsp   = (const float*)d_in[1];
    const float* Xseq  = (const float*)d_in[2];
    const float* S     = (const float*)d_in[3];
    const float* R     = (const float*)d_in[4];
    const float* emb   = (const float*)d_in[5];
    const float* xrepw = (const float*)d_in[6];
    const float* Qw    = (const float*)d_in[7];
    const float* Qb    = (const float*)d_in[8];
    const float* Kw    = (const float*)d_in[9];
    const float* Kb    = (const float*)d_in[10];
    // d_in[11], d_in[12] = Vw, Vb : dead code in reference (attn@V unused)
    const float* ws1   = (const float*)d_in[13];
    const float* bs1   = (const float*)d_in[14];
    const float* wx2   = (const float*)d_in[15];
    const float* bx2   = (const float*)d_in[16];
    const float* wsx33 = (const float*)d_in[17];
    const float* bsx33 = (const float*)d_in[18];
    const float* wr1   = (const float*)d_in[19];
    const float* br1   = (const float*)d_in[20];
    const float* wxx2  = (const float*)d_in[21];
    const float* bxx2  = (const float*)d_in[22];
    const float* wrx33 = (const float*)d_in[23];
    const float* brx33 = (const float*)d_in[24];
    const float* fc1w  = (const float*)d_in[25];
    const float* fc1b  = (const float*)d_in[26];
    const float* fc2w  = (const float*)d_in[27];
    const float* fc2b  = (const float*)d_in[28];
    const float* fc3w  = (const float*)d_in[29];
    const float* fc3b  = (const float*)d_in[30];

    char* ws = (char*)d_ws;
    ushort_t* wbf = (ushort_t*)(ws);            // 384*64*2 = 49152 B (zero-padded tail)
    float*    MTp = (float*)(ws + 49152);       // 64*64*4  = 16384 B
    float*    u0  = (float*)(ws + 65536);       // 256 B
    float*    v0  = (float*)(ws + 65792);       // 256 B
    float*    cS  = (float*)(ws + 66048);       // 4 B

    prep_w<<<(FPAD * HDIM + 255) / 256, 256, 0, stream>>>(xrepw, wbf);
    prep_m<<<17, 256, 0, stream>>>(Qw, Qb, Kw, Kb, MTp, u0, v0, cS);
    fused_model<<<BATCH, 256, 0, stream>>>(
        X, Xsp, Xseq, S, R, emb, xrepw,
        ws1, bs1, wx2, bx2, wsx33, bsx33,
        wr1, br1, wxx2, bxx2, wrx33, brx33,
        fc1w, fc1b, fc2w, fc2b, fc3w, fc3b,
        wbf, MTp, u0, v0, cS, (float*)d_out);
}

// Round 7
// 357.816 us; speedup vs baseline: 1.5102x; 1.0122x over previous
//
#include <hip/hip_runtime.h>
#include <hip/hip_bf16.h>

#define BATCH 1024
#define FDIM  352
#define FPAD  384
#define HDIM  64
#define NT    22          // real n-tiles (g < 352)
#define PDUMMY (FDIM * 64)   // dummy zone inside plds for padded-tile redirect

typedef short bf16x8 __attribute__((ext_vector_type(8)));
typedef float f32x4  __attribute__((ext_vector_type(4)));
typedef unsigned short ushort_t;

__device__ __forceinline__ ushort_t f2bf(float x) {
    union { float f; unsigned u; } v; v.f = x;
    unsigned u = v.u;
    unsigned r = u + 0x7FFFu + ((u >> 16) & 1u);   // RNE to bf16
    return (ushort_t)(r >> 16);
}

__device__ __forceinline__ float sigmoidf_(float x) {
    return 1.0f / (1.0f + __expf(-x));
}

// ---------- prep 1: W (x_rep_w) fp32 -> bf16, padded to 384 rows (zero tail) ----------
__global__ void prep_w(const float* __restrict__ xrepw, ushort_t* __restrict__ wbf) {
    int idx = blockIdx.x * 256 + threadIdx.x;
    if (idx < FPAD * HDIM) {
        int f = idx >> 6;
        wbf[idx] = (f < FDIM) ? f2bf(xrepw[idx]) : (ushort_t)0;
    }
}

// ---------- prep 2: MT[h][d] = sum_e Qw[e,d]*Kw[e,h]; u0,v0,c ----------
__global__ void prep_m(const float* __restrict__ Qw, const float* __restrict__ Qb,
                       const float* __restrict__ Kw, const float* __restrict__ Kb,
                       float* __restrict__ MT, float* __restrict__ u0,
                       float* __restrict__ v0, float* __restrict__ cS) {
    __shared__ float qs[4096], ks[4096];
    const int t = threadIdx.x, blk = blockIdx.x;
    for (int i = t; i < 4096; i += 256) { qs[i] = Qw[i]; ks[i] = Kw[i]; }
    __syncthreads();
    if (blk < 16) {
        int idx = blk * 256 + t;
        int h = idx >> 6, d = idx & 63;
        float acc = 0.f;
        for (int e = 0; e < 64; ++e) acc = fmaf(qs[e * 64 + d], ks[e * 64 + h], acc);
        MT[h * 64 + d] = acc;
    } else {
        if (t < 64) {
            float a = 0.f;
            for (int e = 0; e < 64; ++e) a = fmaf(qs[e * 64 + t], Kb[e], a);
            u0[t] = a;
        } else if (t < 128) {
            int d = t - 64; float a = 0.f;
            for (int e = 0; e < 64; ++e) a = fmaf(ks[e * 64 + d], Qb[e], a);
            v0[d] = a;
        } else if (t == 128) {
            float a = 0.f;
            for (int e = 0; e < 64; ++e) a = fmaf(Qb[e], Kb[e], a);
            cS[0] = a;
        }
    }
}

// ---------- main fused kernel: one workgroup (4 waves) per batch row ----------
// No runtime control flow in G1/G2 tile loops (spill hazard, rounds 3-4). The
// last unrolled copy (imt=5) redirects padded rows (f>=352) to a zeroed dummy
// LDS zone via branchless address select — keeps plds at 352 rows so total LDS
// = 53,760 B -> 3 blocks/CU (was 57,856 B -> 2 blocks/CU, latency-bound).
__global__ __launch_bounds__(256, 2) void fused_model(
    const float* __restrict__ X,    const float* __restrict__ Xsp,  const float* __restrict__ Xseq,
    const float* __restrict__ S,    const float* __restrict__ R,
    const float* __restrict__ emb,  const float* __restrict__ xrepw,
    const float* __restrict__ ws1,  const float* __restrict__ bs1,
    const float* __restrict__ wx2,  const float* __restrict__ bx2,
    const float* __restrict__ wsx33,const float* __restrict__ bsx33,
    const float* __restrict__ wr1,  const float* __restrict__ br1,
    const float* __restrict__ wxx2, const float* __restrict__ bxx2,
    const float* __restrict__ wrx33,const float* __restrict__ brx33,
    const float* __restrict__ fc1w, const float* __restrict__ fc1b,
    const float* __restrict__ fc2w, const float* __restrict__ fc2b,
    const float* __restrict__ fc3w, const float* __restrict__ fc3b,
    const ushort_t* __restrict__ wbf, const float* __restrict__ MT,
    const float* __restrict__ u0g,  const float* __restrict__ v0g,
    const float* __restrict__ cS,   float* __restrict__ out)
{
    __shared__ __align__(16) ushort_t plds[FDIM * 64 + 128]; // P bf16, XOR-swizzled + dummy zone
    __shared__ float xc[FPAD];                           // zero tail 352..383
    __shared__ float pu[FPAD], pv[FPAD];
    __shared__ float outa[384];                          // X_attn (352) + sx(16) + rx(16)
    __shared__ float rnorm[HDIM];
    __shared__ float hx[2][HDIM];
    __shared__ float ph[4][HDIM];                        // also aliased as norm partials
    __shared__ float a1[HDIM], a2[HDIM];

    const int b   = blockIdx.x;
    const int t   = threadIdx.x;
    const int l   = t & 63;
    const int wv  = t >> 6;
    const int row = l & 15;
    const int kg  = l >> 4;

    // ---------- Phase A: build Xc (zero-padded), zero outa + plds dummy zone ----------
    for (int f = t; f < FPAD; f += 256) {
        float v;
        if (f < 64)       v = X[b * 64 + f];
        else if (f < 320) { int i = (f - 64) >> 3, j = (f - 64) & 7; v = Xsp[b * 32 + i] * emb[i * 8 + j]; }
        else if (f < 352) v = Xseq[b * 32 + (f - 320)];
        else              v = 0.f;
        xc[f] = v;
    }
    for (int f = t; f < 384; f += 256) outa[f] = 0.f;
    if (t < 128) plds[PDUMMY + t] = 0;
    __syncthreads();

    // ---------- Phase B: rnorm[d] = 1/||Xrep[:,d]|| (fp32) ----------
    {
        float acc = 0.f;
        for (int f = wv; f < FDIM; f += 4) {
            float v = xc[f] * xrepw[f * 64 + l];
            acc = fmaf(v, v, acc);
        }
        float* pf = &ph[0][0];
        pf[wv * 64 + l] = acc;
        __syncthreads();
        if (t < 64) rnorm[t] = rsqrtf(pf[t] + pf[64 + t] + pf[128 + t] + pf[192 + t]);
        __syncthreads();
    }

    // ---------- Phase C: B-frags of [Mtilde | u~ | v~] (5 n-tiles), bf16, in regs ----------
    bf16x8 bm[5][2];
    {
        float rd[16];
        #pragma unroll
        for (int s = 0; s < 2; ++s)
            #pragma unroll
            for (int j = 0; j < 8; ++j)
                rd[s * 8 + j] = rnorm[s * 32 + kg * 8 + j];
        #pragma unroll
        for (int n = 0; n < 4; ++n) {
            const float rh = rnorm[n * 16 + row] * 0.125f;
            #pragma unroll
            for (int s = 0; s < 2; ++s) {
                const f32x4* mp = (const f32x4*)&MT[(n * 16 + row) * 64 + s * 32 + kg * 8];
                f32x4 m0 = mp[0], m1 = mp[1];
                bf16x8 v;
                #pragma unroll
                for (int j = 0; j < 4; ++j) {
                    v[j]     = (short)f2bf(rd[s * 8 + j]     * m0[j] * rh);
                    v[j + 4] = (short)f2bf(rd[s * 8 + j + 4] * m1[j] * rh);
                }
                bm[n][s] = v;
            }
        }
        #pragma unroll
        for (int s = 0; s < 2; ++s) {
            bf16x8 v = {0, 0, 0, 0, 0, 0, 0, 0};
            if (row < 2) {
                const float* src = (row == 0) ? u0g : v0g;
                const f32x4* up = (const f32x4*)&src[s * 32 + kg * 8];
                f32x4 a0 = up[0], a1v = up[1];
                #pragma unroll
                for (int j = 0; j < 4; ++j) {
                    v[j]     = (short)f2bf(rd[s * 8 + j]     * a0[j]  * 0.125f);
                    v[j + 4] = (short)f2bf(rd[s * 8 + j + 4] * a1v[j] * 0.125f);
                }
            }
            bm[4][s] = v;
        }
    }

    // ---------- Phase G1: P = W @ [Mtilde | u~ | v~]  ->  plds (bf16) + pu/pv (fp32) ----------
    // 24 m-tiles unconditional; padded tiles (imt=5, wv>=2) store zeros to the dummy zone
    // via branchless address select (mt<NT folds to true for imt<5).
    #pragma unroll
    for (int imt = 0; imt < 6; ++imt) {
        const int mt = wv + imt * 4;
        const int f0 = mt * 16;
        const bf16x8 aw0 = *(const bf16x8*)&wbf[(f0 + row) * 64 + kg * 8];
        const bf16x8 aw1 = *(const bf16x8*)&wbf[(f0 + row) * 64 + 32 + kg * 8];
        f32x4 p[5];
        #pragma unroll
        for (int n = 0; n < 5; ++n) {
            f32x4 a = {0.f, 0.f, 0.f, 0.f};
            a = __builtin_amdgcn_mfma_f32_16x16x32_bf16(aw0, bm[n][0], a, 0, 0, 0);
            a = __builtin_amdgcn_mfma_f32_16x16x32_bf16(aw1, bm[n][1], a, 0, 0, 0);
            p[n] = a;
        }
        #pragma unroll
        for (int r = 0; r < 4; ++r) {
            const int f = f0 + kg * 4 + r;
            const int sw = (f & 7) << 3;
            #pragma unroll
            for (int n = 0; n < 4; ++n) {
                const int idx = (mt < NT) ? (f * 64 + ((n * 16 + row) ^ sw)) : (PDUMMY + l);
                plds[idx] = f2bf(p[n][r]);
            }
            if (row == 0)      pu[f] = p[4][r];   // pu/pv sized FPAD: padded rows hold 0
            else if (row == 1) pv[f] = p[4][r];
        }
    }
    __syncthreads();

    // ---------- Phase G2: scores = Xc_f*Xc_g*(P W^T) + Xc_f*Pu_f + Xc_g*Pv_g + c ----------
    //            row-softmax over g (no max pass: |s| = O(1)), accumulate X_attn[g].
    //            Padded rows f>=352 read dummy zeros; xc=0 -> coef=0 -> contribute 0.
    {
        const float cg = cS[0] * 0.125f;
        #pragma unroll
        for (int imt = 0; imt < 6; ++imt) {
            const int mt = wv + imt * 4;
            const int f0 = mt * 16;
            const int swr = (row & 7) << 3;
            const int a0idx = (mt < NT) ? ((f0 + row) * 64 + ((kg * 8) ^ swr))        : PDUMMY;
            const int a1idx = (mt < NT) ? ((f0 + row) * 64 + ((32 + kg * 8) ^ swr))   : PDUMMY;
            const bf16x8 ap0 = *(const bf16x8*)&plds[a0idx];
            const bf16x8 ap1 = *(const bf16x8*)&plds[a1idx];

            f32x4 acc[NT];
            #pragma unroll
            for (int nt = 0; nt < NT; ++nt) {
                const int g = nt * 16 + row;
                bf16x8 b0 = *(const bf16x8*)&wbf[g * 64 + kg * 8];
                bf16x8 b1 = *(const bf16x8*)&wbf[g * 64 + 32 + kg * 8];
                f32x4 a = {0.f, 0.f, 0.f, 0.f};
                a = __builtin_amdgcn_mfma_f32_16x16x32_bf16(ap0, b0, a, 0, 0, 0);
                a = __builtin_amdgcn_mfma_f32_16x16x32_bf16(ap1, b1, a, 0, 0, 0);
                acc[nt] = a;
            }

            float xf[4], uf[4];
            #pragma unroll
            for (int r = 0; r < 4; ++r) {
                const int f = f0 + kg * 4 + r;
                xf[r] = xc[f];
                uf[r] = fmaf(xf[r], pu[f], cg);
            }
            float lsum[4] = {0.f, 0.f, 0.f, 0.f};
            #pragma unroll
            for (int nt = 0; nt < NT; ++nt) {
                const int g = nt * 16 + row;
                const float xg = xc[g];
                const float vg = xg * pv[g];
                #pragma unroll
                for (int r = 0; r < 4; ++r) {
                    float s = fmaf(xf[r] * xg, acc[nt][r], uf[r] + vg);
                    float p = __expf(s);
                    acc[nt][r] = p;
                    lsum[r] += p;
                }
            }
            #pragma unroll
            for (int r = 0; r < 4; ++r) {
                #pragma unroll
                for (int off = 1; off < 16; off <<= 1)
                    lsum[r] += __shfl_xor(lsum[r], off, 64);
            }
            float coef[4];
            #pragma unroll
            for (int r = 0; r < 4; ++r) coef[r] = xf[r] / lsum[r];
            #pragma unroll
            for (int nt = 0; nt < NT; ++nt) {
                float po = coef[0] * acc[nt][0] + coef[1] * acc[nt][1]
                         + coef[2] * acc[nt][2] + coef[3] * acc[nt][3];
                po += __shfl_xor(po, 16, 64);
                po += __shfl_xor(po, 32, 64);
                if (l < 16) atomicAdd(&outa[nt * 16 + l], po);
            }
        }
    }
    __syncthreads();

    // ---------- Phase H: h_x = sigmoid(Xc @ w2^T + b2), both branches, 4 waves ----------
    {
        const int br = wv >> 1, fh = wv & 1;
        const float* w2 = br ? wxx2 : wx2;
        const int fo = l & 3, hb = l >> 2;
        float acc[4] = {0.f, 0.f, 0.f, 0.f};
        for (int k = 0; k < 44; ++k) {
            const int f = fh * 176 + fo + k * 4;
            const float xv = xc[f];
            #pragma unroll
            for (int c = 0; c < 4; ++c)
                acc[c] = fmaf(xv, w2[(hb + 16 * c) * FDIM + f], acc[c]);
        }
        #pragma unroll
        for (int c = 0; c < 4; ++c) {
            acc[c] += __shfl_xor(acc[c], 1, 64);
            acc[c] += __shfl_xor(acc[c], 2, 64);
        }
        if (fo == 0) {
            #pragma unroll
            for (int c = 0; c < 4; ++c) ph[wv][hb + 16 * c] = acc[c];
        }
    }
    __syncthreads();
    if (t < 128) {
        const int br = t >> 6, h = t & 63;
        const float* b2 = br ? bxx2 : bx2;
        hx[br][h] = sigmoidf_(ph[br * 2][h] + ph[br * 2 + 1][h] + b2[h]);
    }
    __syncthreads();

    // ---------- Phase I: interaction attention (wave0=S, wave1=R) ----------
    if (wv < 2) {
        const float* sv  = wv ? R     : S;
        const float* w1  = wv ? wr1   : ws1;
        const float* b1  = wv ? br1   : bs1;
        const float* w33 = wv ? wrx33 : wsx33;
        const float  b33 = wv ? brx33[0] : bsx33[0];
        const int i = l >> 2, ho = l & 3;
        const float si = sv[b * 16 + i];
        float v = 0.f;
        for (int k = 0; k < 16; ++k) {
            const int h = ho * 16 + k;
            float hs = sigmoidf_(fmaf(si, w1[h], b1[h]));
            v = fmaf(fmaxf(hs + hx[wv][h], 0.f), w33[h], v);
        }
        v += __shfl_xor(v, 1, 64);
        v += __shfl_xor(v, 2, 64);
        const float sc = v + b33;
        float mm = sc;
        #pragma unroll
        for (int off = 4; off < 64; off <<= 1) mm = fmaxf(mm, __shfl_xor(mm, off, 64));
        const float p = __expf(sc - mm);
        float ss = p;
        #pragma unroll
        for (int off = 4; off < 64; off <<= 1) ss += __shfl_xor(ss, off, 64);
        if (ho == 0) outa[FDIM + wv * 16 + i] = si * (p / ss);
    }
    __syncthreads();

    // ---------- Phase J: MLP head ----------
    {   // fc1: [64 x 384]
        const int h = t >> 2, jo = t & 3;
        float acc = 0.f;
        for (int j = jo; j < 384; j += 4)
            acc = fmaf(outa[j], fc1w[h * 384 + j], acc);
        acc += __shfl_xor(acc, 1, 64);
        acc += __shfl_xor(acc, 2, 64);
        if (jo == 0) a1[h] = fmaxf(acc + fc1b[h], 0.f);
    }
    __syncthreads();
    {   // fc2: [64 x 64]
        const int h = t >> 2, jo = t & 3;
        float acc = 0.f;
        #pragma unroll
        for (int j = jo; j < 64; j += 4)
            acc = fmaf(a1[j], fc2w[h * 64 + j], acc);
        acc += __shfl_xor(acc, 1, 64);
        acc += __shfl_xor(acc, 2, 64);
        if (jo == 0) a2[h] = fmaxf(acc + fc2b[h], 0.f);
    }
    __syncthreads();
    if (wv == 0) {   // fc3: [1 x 64]
        float v = fc3w[l] * a2[l];
        #pragma unroll
        for (int off = 1; off < 64; off <<= 1) v += __shfl_xor(v, off, 64);
        if (l == 0) out[b] = v + fc3b[0];
    }
}

extern "C" void kernel_launch(void* const* d_in, const int* in_sizes, int n_in,
                              void* d_out, int out_size, void* d_ws, size_t ws_size,
                              hipStream_t stream) {
    const float* X     = (const float*)d_in[0];
    const float* Xsp   = (const float*)d_in[1];
    const float* Xseq  = (const float*)d_in[2];
    const float* S     = (const float*)d_in[3];
    const float* R     = (const float*)d_in[4];
    const float* emb   = (const float*)d_in[5];
    const float* xrepw = (const float*)d_in[6];
    const float* Qw    = (const float*)d_in[7];
    const float* Qb    = (const float*)d_in[8];
    const float* Kw    = (const float*)d_in[9];
    const float* Kb    = (const float*)d_in[10];
    // d_in[11], d_in[12] = Vw, Vb : dead code in reference (attn@V unused)
    const float* ws1   = (const float*)d_in[13];
    const float* bs1   = (const float*)d_in[14];
    const float* wx2   = (const float*)d_in[15];
    const float* bx2   = (const float*)d_in[16];
    const float* wsx33 = (const float*)d_in[17];
    const float* bsx33 = (const float*)d_in[18];
    const float* wr1   = (const float*)d_in[19];
    const float* br1   = (const float*)d_in[20];
    const float* wxx2  = (const float*)d_in[21];
    const float* bxx2  = (const float*)d_in[22];
    const float* wrx33 = (const float*)d_in[23];
    const float* brx33 = (const float*)d_in[24];
    const float* fc1w  = (const float*)d_in[25];
    const float* fc1b  = (const float*)d_in[26];
    const float* fc2w  = (const float*)d_in[27];
    const float* fc2b  = (const float*)d_in[28];
    const float* fc3w  = (const float*)d_in[29];
    const float* fc3b  = (const float*)d_in[30];

    char* ws = (char*)d_ws;
    ushort_t* wbf = (ushort_t*)(ws);            // 384*64*2 = 49152 B (zero-padded tail)
    float*    MTp = (float*)(ws + 49152);       // 64*64*4  = 16384 B
    float*    u0  = (float*)(ws + 65536);       // 256 B
    float*    v0  = (float*)(ws + 65792);       // 256 B
    float*    cS  = (float*)(ws + 66048);       // 4 B

    prep_w<<<(FPAD * HDIM + 255) / 256, 256, 0, stream>>>(xrepw, wbf);
    prep_m<<<17, 256, 0, stream>>>(Qw, Qb, Kw, Kb, MTp, u0, v0, cS);
    fused_model<<<BATCH, 256, 0, stream>>>(
        X, Xsp, Xseq, S, R, emb, xrepw,
        ws1, bs1, wx2, bx2, wsx33, bsx33,
        wr1, br1, wxx2, bxx2, wrx33, brx33,
        fc1w, fc1b, fc2w, fc2b, fc3w, fc3b,
        wbf, MTp, u0, v0, cS, (float*)d_out);
}